// Round 17
// baseline (292.988 us; speedup 1.0000x reference)
//
#include <hip/hip_runtime.h>
#include <hip/hip_bf16.h>
#include <cstdint>

// ParaNet_Point round-17: conv3 = 8-wave + BK=64 + load-shadowed bfr.
// r16 lesson: 4 waves/SIMD reached (occ 39.6%) but MfmaUtil flat -> the
// binding term is the per-barrier serial chain x n_barriers. Compose:
//   8-wave (acc=32, occupancy band proven by r16)
// + BK=64 (16 MFMA/wave/barrier, 34 barriers vs 68 -- r15 alone was neutral
//   only because 2 waves/SIMD had no slack to use)
// + bfr0/bfr1 loaded right after barrier, consumed after 72-pkfma buildA
//   shadow (covers ~250cyc L2 latency).
// conv1/conv2 frozen at r14 4-wave. absmax must remain exactly 0.0078125.

#define GRIDW 256
#define NPTS  65536
#define RADI  0.0125f
#define EPSF  1e-12f

typedef unsigned short ushort_t;
typedef unsigned int   uint_t;
typedef __attribute__((ext_vector_type(8))) short short8;   // 8 bf16 = 4 VGPR
typedef __attribute__((ext_vector_type(4))) float f32x4;
typedef __attribute__((ext_vector_type(2))) float f32x2;

template<int N> struct IC { static constexpr int v = N; };

__device__ __forceinline__ float bf2f(ushort_t h){
  union { uint_t u; float f; } c; c.u = ((uint_t)h) << 16; return c.f;
}
__device__ __forceinline__ ushort_t f2bf(float f){
  union { float f; uint_t u; } c; c.f = f;
  uint_t u = c.u;
  u += 0x7fffu + ((u >> 16) & 1u);   // round-to-nearest-even
  return (ushort_t)(u >> 16);
}
__device__ __forceinline__ uint_t cvtpk(float a, float b){   // {bf16(b)<<16 | bf16(a)}
  uint_t r; asm("v_cvt_pk_bf16_f32 %0, %1, %2" : "=v"(r) : "v"(a), "v"(b)); return r;
}
// dual-f32 fma, value-low broadcast: d{lo,hi} += t{lo,hi} * v.lo
__device__ __forceinline__ void pkfma_lo(f32x2& d, f32x2 t, f32x2 v){
  asm("v_pk_fma_f32 %0, %1, %2, %0 op_sel:[0,0,0] op_sel_hi:[1,0,1]"
      : "+v"(d) : "v"(t), "v"(v));
}
// dual-f32 fma, value-high broadcast: d{lo,hi} += t{lo,hi} * v.hi
__device__ __forceinline__ void pkfma_hi(f32x2& d, f32x2 t, f32x2 v){
  asm("v_pk_fma_f32 %0, %1, %2, %0 op_sel:[0,1,0] op_sel_hi:[1,1,1]"
      : "+v"(d) : "v"(t), "v"(v));
}
// swizzled byte offset into 64B-row LDS tile (row-dep XOR of 16B slot)
__device__ __forceinline__ int swz(int row, int byteoff){
  return row*64 + ((((byteoff >> 4) ^ ((row >> 1) & 3)) & 3) << 4) + (byteoff & 15);
}

// ---------------- BatchNorm statistics ----------------
__global__ __launch_bounds__(256) void bn_partial(const float2* __restrict__ vel,
                                                  float* __restrict__ part){
  __shared__ float s[256][4];
  const int t = threadIdx.x;
  const int id = blockIdx.x * 256 + t;
  float2 v = vel[id];
  s[t][0] = v.x; s[t][1] = v.y; s[t][2] = v.x * v.x; s[t][3] = v.y * v.y;
  __syncthreads();
  for (int off = 128; off > 0; off >>= 1){
    if (t < off){
      s[t][0] += s[t+off][0]; s[t][1] += s[t+off][1];
      s[t][2] += s[t+off][2]; s[t][3] += s[t+off][3];
    }
    __syncthreads();
  }
  if (t == 0){
    part[blockIdx.x*4+0] = s[0][0]; part[blockIdx.x*4+1] = s[0][1];
    part[blockIdx.x*4+2] = s[0][2]; part[blockIdx.x*4+3] = s[0][3];
  }
}

__global__ __launch_bounds__(256) void bn_final(const float* __restrict__ part,
                                                const float* __restrict__ gamma,
                                                const float* __restrict__ beta,
                                                float* __restrict__ stats){
  __shared__ float s[256][4];
  const int t = threadIdx.x;
  const float4 p = reinterpret_cast<const float4*>(part)[t];
  s[t][0] = p.x; s[t][1] = p.y; s[t][2] = p.z; s[t][3] = p.w;
  __syncthreads();
  for (int off = 128; off > 0; off >>= 1){
    if (t < off){
      s[t][0] += s[t+off][0]; s[t][1] += s[t+off][1];
      s[t][2] += s[t+off][2]; s[t][3] += s[t+off][3];
    }
    __syncthreads();
  }
  if (t == 0){
    const float invN = 1.0f / 65536.0f;
    float m0 = s[0][0]*invN, m1 = s[0][1]*invN;
    float var0 = s[0][2]*invN - m0*m0;
    float var1 = s[0][3]*invN - m1*m1;
    float A0 = gamma[0] * rsqrtf(var0 + 1e-5f);
    float A1 = gamma[1] * rsqrtf(var1 + 1e-5f);
    stats[0] = A0; stats[1] = beta[0] - A0*m0;
    stats[2] = A1; stats[3] = beta[1] - A1*m1;
    stats[4] = beta[2];   // z-col of vel3 is identically 0
  }
}

__global__ __launch_bounds__(256) void feats_kernel(const float2* __restrict__ vel,
                                                    const float* __restrict__ stats,
                                                    float4* __restrict__ fin){
  const int id = blockIdx.x * 256 + threadIdx.x;
  float2 v = vel[id];
  float A0 = stats[0], B0 = stats[1], A1 = stats[2], B1 = stats[3], C2 = stats[4];
  fin[id] = make_float4(A0*v.x + B0, A1*v.y + B1, C2, 0.0f);
}

// ---------------- filter geometry: (win, gx, gy) per (n,k) ----------------
__global__ __launch_bounds__(256) void geo_kernel(const float2* __restrict__ pos,
                                                  float4* __restrict__ wgeo){
  const int id = blockIdx.x * 256 + threadIdx.x;   // < N*9 exactly
  const int n = id / 9;
  const int k = id - n * 9;
  const int i = n >> 8, j = n & 255;
  const int di = k / 3 - 1, dj = k - (k/3)*3 - 1;
  const int ni = i + di, nj = j + dj;
  const bool valid = (ni >= 0) && (ni < GRIDW) && (nj >= 0) && (nj < GRIDW);
  const int mi = min(max(ni, 0), GRIDW-1), mj = min(max(nj, 0), GRIDW-1);
  const int m = (mi << 8) | mj;
  float2 pn = pos[n], pm = pos[m];
  float x = (pm.x - pn.x) * (1.0f / RADI);
  float y = (pm.y - pn.y) * (1.0f / RADI);
  float sq = x*x + y*y;                 // z == 0 throughout
  bool nz = sq > EPSF;
  float cx = nz ? x : 0.0f;
  float cy = nz ? y : 0.0f;
  float rr = cx*cx + cy*cy;
  float r = sqrtf(fmaxf(rr, EPSF));
  float acx = fabsf(cx), acy = fabsf(cy);
  bool condx = acx >= acy;
  float dx  = (acx > 1e-9f) ? cx : 1.0f;
  float dyv = (acy > 1e-9f) ? cy : 1.0f;
  const float fop = 1.27323954473516268615f;   // 4/pi
  float sx = (cx > 0.f) ? 1.f : ((cx < 0.f) ? -1.f : 0.f);
  float sy = (cy > 0.f) ? 1.f : ((cy < 0.f) ? -1.f : 0.f);
  float u, v;
  if (condx){ u = sx * r;                    v = sx * r * fop * atanf(cy/dx); }
  else      { u = sy * r * fop * atanf(cx/dyv); v = sy * r; }
  if (rr <= EPSF){ u = 0.0f; v = 0.0f; }
  float gx = fminf(fmaxf((u + 1.0f) * 1.5f, 0.0f), 3.0f);
  float gy = fminf(fmaxf((v + 1.0f) * 1.5f, 0.0f), 3.0f);
  float pw = 1.0f - fminf(fmaxf(sq, 0.0f), 1.0f);
  float win = pw * pw * pw;
  win = (sq <= 1.0f && valid) ? win : 0.0f;
  wgeo[id] = make_float4(win, gx, gy, 0.0f);
}

// -- W pre-pack into MFMA B-fragment order --------------------------------
template<int Cin, int Cout>
__global__ __launch_bounds__(256) void wprep(const float* __restrict__ cw,
                                             const float* __restrict__ dw,
                                             ushort_t* __restrict__ Wf){
  constexpr int G = Cout/16;
  const int id = blockIdx.x*256 + threadIdx.x;     // grid sized exactly
  const int ch = id / (G*64);
  const int r  = id - ch*G*64;
  const int grp = r >> 6, l = r & 63;
  const int d  = grp*16 + (l & 15);
  const int kb = ch*32 + (l >> 4)*8;
  ushort_t o[8];
  #pragma unroll
  for (int e = 0; e < 8; ++e){
    const int kk = kb + e;
    float v;
    if (kk < 16*Cin){ int c = kk >> 4, g = kk & 15; v = cw[(size_t)(g*Cin + c)*Cout + d]; }
    else v = dw[(size_t)(kk - 16*Cin)*Cout + d];
    o[e] = f2bf(v);
  }
  *reinterpret_cast<uint4*>(Wf + (size_t)id*8) = *reinterpret_cast<uint4*>(o);
}

// ---------------- layer 0: Cin=3 direct (VALU, small) ----------------
__global__ __launch_bounds__(256) void layer0_kernel(
    const float4* __restrict__ fin, const float4* __restrict__ wgeo,
    const float* __restrict__ cw, const float* __restrict__ cb,
    const float* __restrict__ dw, const float* __restrict__ db,
    ushort_t* __restrict__ f0){
  __shared__ float Wc[48*32];
  __shared__ float Wd[96];
  __shared__ float Bs[64];
  const int tid = threadIdx.x;
  for (int idx = tid; idx < 1536; idx += 256) Wc[idx] = cw[idx];
  if (tid < 96) Wd[tid] = dw[tid];
  if (tid < 32){ Bs[tid] = cb[tid]; Bs[32+tid] = db[tid]; }
  __syncthreads();
  const int p = tid >> 3, q = tid & 7;
  const int n = blockIdx.x * 32 + p;
  const int i = n >> 8, j = n & 255;
  float A[48];
  #pragma unroll
  for (int a = 0; a < 48; ++a) A[a] = 0.0f;
  const float4 fc = fin[n];
  #pragma unroll
  for (int k = 0; k < 9; ++k){
    const int di = k/3 - 1, dj = k - (k/3)*3 - 1;
    const int mi = min(max(i+di,0),255), mj = min(max(j+dj,0),255);
    const int m = (mi << 8) | mj;
    float4 geo = wgeo[n*9 + k];
    float4 fm = fin[m];
    float wx[4], wy[4];
    #pragma unroll
    for (int a = 0; a < 4; ++a){
      wx[a] = fmaxf(1.0f - fabsf(geo.y - (float)a), 0.0f);
      wy[a] = fmaxf(1.0f - fabsf(geo.z - (float)a), 0.0f);
    }
    #pragma unroll
    for (int ix = 0; ix < 4; ++ix)
      #pragma unroll
      for (int iy = 0; iy < 4; ++iy){
        float w = geo.x * wx[ix] * wy[iy];
        int g = ix*4 + iy;
        A[g*3+0] += w * fm.x; A[g*3+1] += w * fm.y; A[g*3+2] += w * fm.z;
      }
  }
  if (q < 4){
    #pragma unroll
    for (int jj = 0; jj < 8; ++jj){
      int d = q*8 + jj;
      float acc = Bs[d];
      #pragma unroll
      for (int a = 0; a < 48; ++a) acc += A[a] * Wc[a*32 + d];
      f0[n*64 + d] = f2bf(acc);
    }
  } else {
    #pragma unroll
    for (int jj = 0; jj < 8; ++jj){
      int d2 = (q-4)*8 + jj;
      float acc = Bs[32+d2] + fc.x*Wd[0*32+d2] + fc.y*Wd[1*32+d2] + fc.z*Wd[2*32+d2];
      f0[n*64 + 32 + d2] = f2bf(acc);
    }
  }
}

// ---- 4-wave MFMA conv (r14, proven): conv1/conv2 ----
template<int Cin, int Cout, bool RESID>
__global__ __launch_bounds__(256) void conv_mfma(
    const ushort_t* __restrict__ fin, const float4* __restrict__ wgeo,
    const ushort_t* __restrict__ Wf,
    const float* __restrict__ cb, const float* __restrict__ db,
    ushort_t* __restrict__ fout){
  constexpr int K   = 17*Cin;
  constexpr int NCC = Cin/2;
  constexpr int NCH = K/32;
  constexpr int HSTR = 137;
  constexpr int G   = Cout/16;
  constexpr int MF  = 4;
  constexpr int NF  = Cout/64;

  __shared__ f32x2 halo64[16*HSTR];
  __shared__ __align__(16) ushort_t A_lds[2][64*32];

  const int tid = threadIdx.x;
  const int i0 = (blockIdx.x >> 3) * 2;
  const int j0 = (blockIdx.x & 7) * 32;

  auto stage = [&](int ph){
    for (int idx = tid; idx < 544; idx += 256){
      const int loc = idx >> 2, c8l = idx & 3;
      const int r = loc / 34, col = loc - r*34;
      const int gi = min(max(i0 - 1 + r, 0), 255);
      const int gj = min(max(j0 - 1 + col, 0), 255);
      const int mm = (gi << 8) | gj;
      uint4 v = *reinterpret_cast<const uint4*>(fin + (size_t)mm*Cin + ph*32 + c8l*8);
      const uint_t* vp = (const uint_t*)&v;
      #pragma unroll
      for (int q = 0; q < 4; ++q){
        uint_t u = vp[q];
        f32x2 f;
        f.x = fmaxf(__uint_as_float(u << 16), 0.0f);
        f.y = fmaxf(__uint_as_float(u & 0xFFFF0000u), 0.0f);
        halo64[(c8l*4 + q)*HSTR + loc] = f;
      }
    }
  };

  const int m  = tid & 63;
  const int gq = tid >> 6;
  const int g0 = gq * 4;
  const int n_m = ((i0 + (m >> 5)) << 8) + j0 + (m & 31);
  const int lane = m;
  const int lr = lane & 15, lg = lane >> 4;
  const int ctr = (1 + (m >> 5))*34 + 1 + (m & 31);

  stage(0);
  f32x2 tap2[9][2];
  #pragma unroll
  for (int k = 0; k < 9; ++k){
    float4 geo = wgeo[(size_t)n_m*9 + k];
    float wxg = fmaxf(1.0f - fabsf(geo.y - (float)gq), 0.0f);
    float s = geo.x * wxg;
    tap2[k][0].x = s * fmaxf(1.0f - fabsf(geo.z - 0.0f), 0.0f);
    tap2[k][0].y = s * fmaxf(1.0f - fabsf(geo.z - 1.0f), 0.0f);
    tap2[k][1].x = s * fmaxf(1.0f - fabsf(geo.z - 2.0f), 0.0f);
    tap2[k][1].y = s * fmaxf(1.0f - fabsf(geo.z - 3.0f), 0.0f);
  }

  const int Nbase = gq * (NF*16);

  int aoff[MF];
  #pragma unroll
  for (int mi = 0; mi < MF; ++mi) aoff[mi] = swz(mi*16 + lr, lg*16);
  const int s0 = swz(m, 2*g0);
  const int s1 = swz(m, 32 + 2*g0);
  const int sd = swz(m, gq*16);

  const ushort_t* wp = Wf + (size_t)(gq*NF)*512 + lane*8;

  f32x4 acc[MF][NF];
  #pragma unroll
  for (int a = 0; a < MF; ++a)
    #pragma unroll
    for (int b = 0; b < NF; ++b) acc[a][b] = (f32x4){0.f,0.f,0.f,0.f};

  short8 bfrA[NF], bfrB[NF];
  auto loadB = [&](short8 (&dst)[NF], int ch){
    const ushort_t* wpc = wp + (size_t)ch * (G*512);
    #pragma unroll
    for (int ni = 0; ni < NF; ++ni)
      dst[ni] = *reinterpret_cast<const short8*>(wpc + ni*512);
  };

  auto buildA = [&](auto BC, int ch){
    constexpr int B = decltype(BC)::v;
    char* Ab = (char*)A_lds[B];
    if (ch < NCC){
      const f32x2* hb = &halo64[(ch & 15)*HSTR + ctr - 35];
      f32x2 a01 = {0.f,0.f}, a23 = {0.f,0.f};
      f32x2 b01 = {0.f,0.f}, b23 = {0.f,0.f};
      #pragma unroll
      for (int kr = 0; kr < 3; ++kr)
        #pragma unroll
        for (int kc = 0; kc < 3; ++kc){
          const f32x2 val = hb[kr*34 + kc];
          const int k = kr*3 + kc;
          pkfma_lo(a01, tap2[k][0], val);
          pkfma_lo(a23, tap2[k][1], val);
          pkfma_hi(b01, tap2[k][0], val);
          pkfma_hi(b23, tap2[k][1], val);
        }
      uint2 plo, phi;
      plo.x = cvtpk(a01.x, a01.y); plo.y = cvtpk(a23.x, a23.y);
      phi.x = cvtpk(b01.x, b01.y); phi.y = cvtpk(b23.x, b23.y);
      *reinterpret_cast<uint2*>(Ab + s0) = plo;
      *reinterpret_cast<uint2*>(Ab + s1) = phi;
    } else {
      const int cd0 = (ch - NCC)*32 + gq*8;
      uint4 u = *reinterpret_cast<const uint4*>(fin + (size_t)n_m*Cin + cd0);
      uint_t* up = (uint_t*)&u;
      #pragma unroll
      for (int q = 0; q < 4; ++q){
        uint_t w = up[q];
        uint_t lo = (w & 0x00008000u) ? 0u : (w & 0x0000FFFFu);
        uint_t hi = (w & 0x80000000u) ? 0u : (w & 0xFFFF0000u);
        up[q] = hi | lo;
      }
      *reinterpret_cast<uint4*>(Ab + sd) = u;
    }
  };

  auto domfma = [&](short8 (&af)[MF], short8 (&bfr)[NF]){
    #pragma unroll
    for (int mi = 0; mi < MF; ++mi)
      #pragma unroll
      for (int ni = 0; ni < NF; ++ni)
        acc[mi][ni] = __builtin_amdgcn_mfma_f32_16x16x32_bf16(
            af[mi], bfr[ni], acc[mi][ni], 0, 0, 0);
  };

  auto body = [&](auto BC, int ch, bool prep){
    constexpr int B = decltype(BC)::v;
    __syncthreads();
    if (prep){
      if constexpr (B == 0) loadB(bfrB, ch + 1);
      else                  loadB(bfrA, ch + 1);
    }
    short8 af[MF];
    const char* Ab = (const char*)A_lds[B];
    #pragma unroll
    for (int mi = 0; mi < MF; ++mi)
      af[mi] = *reinterpret_cast<const short8*>(Ab + aoff[mi]);
    if (prep) buildA(IC<B^1>{}, ch + 1);
    if constexpr (B == 0) domfma(af, bfrA);
    else                  domfma(af, bfrB);
  };

  __syncthreads();
  loadB(bfrA, 0);
  buildA(IC<0>{}, 0);

  for (int ch2 = 0; ch2 < NCH; ch2 += 2){
    body(IC<0>{}, ch2, true);
    const int nxt = ch2 + 2;
    if ((nxt < NCC) && ((nxt & 15) == 0)){ __syncthreads(); stage(nxt >> 4); }
    body(IC<1>{}, ch2 + 1, nxt < NCH);
  }

  float bias[NF];
  #pragma unroll
  for (int ni = 0; ni < NF; ++ni){
    const int d = Nbase + ni*16 + lr;
    bias[ni] = cb[d] + db[d];
  }
  #pragma unroll
  for (int mi = 0; mi < MF; ++mi){
    #pragma unroll
    for (int r = 0; r < 4; ++r){
      const int row = mi*16 + lg*4 + r;
      const int n = ((i0 + (row >> 5)) << 8) + j0 + (row & 31);
      #pragma unroll
      for (int ni = 0; ni < NF; ++ni){
        const int d = Nbase + ni*16 + lr;
        float v = acc[mi][ni][r] + bias[ni];
        if (RESID) v += bf2f(fin[(size_t)n*Cin + d]);
        fout[(size_t)n*Cout + d] = f2bf(v);
      }
    }
  }
}

// ---- 8-wave MFMA conv, BK=64 super-chunks: conv3 ----
// Wave wv: A-build task (cl=wv>>2, gq=wv&3); MFMA cols [wv*32, wv*32+32).
// Per barrier: 16 MFMA/wave; bfr0/bfr1 loaded post-barrier, consumed after
// the 2x buildA VALU shadow.
template<int Cin, int Cout, bool RESID>
__global__ __launch_bounds__(512) void conv_mfma8(
    const ushort_t* __restrict__ fin, const float4* __restrict__ wgeo,
    const ushort_t* __restrict__ Wf,
    const float* __restrict__ cb, const float* __restrict__ db,
    ushort_t* __restrict__ fout){
  constexpr int K   = 17*Cin;
  constexpr int NCC = Cin/2;
  constexpr int NCH = K/32;
  constexpr int NSC = NCH/2;            // BK=64 super-chunks
  constexpr int HSTR = 137;
  constexpr int G   = Cout/16;
  constexpr int MF  = 4;
  constexpr int NF  = Cout/128;         // 8 waves x NF*16 cols

  __shared__ f32x2 halo64[16*HSTR];                 // 17536 B
  __shared__ __align__(16) char A_lds[2*2*4096];    // [buf][half] 4KB tiles

  const int tid = threadIdx.x;
  const int i0 = (blockIdx.x >> 3) * 2;
  const int j0 = (blockIdx.x & 7) * 32;

  auto stage = [&](int ph){
    for (int idx = tid; idx < 544; idx += 512){
      const int loc = idx >> 2, c8l = idx & 3;
      const int r = loc / 34, col = loc - r*34;
      const int gi = min(max(i0 - 1 + r, 0), 255);
      const int gj = min(max(j0 - 1 + col, 0), 255);
      const int mm = (gi << 8) | gj;
      uint4 v = *reinterpret_cast<const uint4*>(fin + (size_t)mm*Cin + ph*32 + c8l*8);
      const uint_t* vp = (const uint_t*)&v;
      #pragma unroll
      for (int q = 0; q < 4; ++q){
        uint_t u = vp[q];
        f32x2 f;
        f.x = fmaxf(__uint_as_float(u << 16), 0.0f);
        f.y = fmaxf(__uint_as_float(u & 0xFFFF0000u), 0.0f);
        halo64[(c8l*4 + q)*HSTR + loc] = f;
      }
    }
  };

  const int m  = tid & 63;              // local point == lane
  const int wv = tid >> 6;              // wave 0..7
  const int gq = wv & 3;                // g-quarter (tap slice)
  const int cl = wv >> 2;               // channel of pair (wave-uniform)
  const int n_m = ((i0 + (m >> 5)) << 8) + j0 + (m & 31);
  const int lane = m;
  const int lr = lane & 15, lg = lane >> 4;
  const int ctr = (1 + (m >> 5))*34 + 1 + (m & 31);

  stage(0);
  f32x2 tap2[9][2];
  #pragma unroll
  for (int k = 0; k < 9; ++k){
    float4 geo = wgeo[(size_t)n_m*9 + k];
    float wxg = fmaxf(1.0f - fabsf(geo.y - (float)gq), 0.0f);
    float s = geo.x * wxg;
    tap2[k][0].x = s * fmaxf(1.0f - fabsf(geo.z - 0.0f), 0.0f);
    tap2[k][0].y = s * fmaxf(1.0f - fabsf(geo.z - 1.0f), 0.0f);
    tap2[k][1].x = s * fmaxf(1.0f - fabsf(geo.z - 2.0f), 0.0f);
    tap2[k][1].y = s * fmaxf(1.0f - fabsf(geo.z - 3.0f), 0.0f);
  }

  const int Nbase = wv * (NF*16);       // wave's unique 32-col block

  int aoff[MF];
  #pragma unroll
  for (int mi = 0; mi < MF; ++mi) aoff[mi] = swz(mi*16 + lr, lg*16);
  const int sc  = swz(m, cl*32 + gq*8); // conv-chunk uint2 slot
  const int sdn = swz(m, wv*8);         // dense-chunk uint2 slot

  const ushort_t* wp = Wf + (size_t)(wv*NF)*512 + lane*8;

  f32x4 acc[MF][NF];
  #pragma unroll
  for (int a = 0; a < MF; ++a)
    #pragma unroll
    for (int b = 0; b < NF; ++b) acc[a][b] = (f32x4){0.f,0.f,0.f,0.f};

  auto loadB = [&](short8 (&dst)[NF], int ch){
    const ushort_t* wpc = wp + (size_t)ch * (G*512);
    #pragma unroll
    for (int ni = 0; ni < NF; ++ni)
      dst[ni] = *reinterpret_cast<const short8*>(wpc + ni*512);
  };

  auto buildA = [&](char* Ab, int ch){
    if (ch < NCC){
      const f32x2* hb = &halo64[(ch & 15)*HSTR + ctr - 35];
      f32x2 a01 = {0.f,0.f}, a23 = {0.f,0.f};
      if (cl == 0){                       // wave-uniform branch
        #pragma unroll
        for (int kr = 0; kr < 3; ++kr)
          #pragma unroll
          for (int kc = 0; kc < 3; ++kc){
            const f32x2 val = hb[kr*34 + kc];
            const int k = kr*3 + kc;
            pkfma_lo(a01, tap2[k][0], val);
            pkfma_lo(a23, tap2[k][1], val);
          }
      } else {
        #pragma unroll
        for (int kr = 0; kr < 3; ++kr)
          #pragma unroll
          for (int kc = 0; kc < 3; ++kc){
            const f32x2 val = hb[kr*34 + kc];
            const int k = kr*3 + kc;
            pkfma_hi(a01, tap2[k][0], val);
            pkfma_hi(a23, tap2[k][1], val);
          }
      }
      uint2 p;
      p.x = cvtpk(a01.x, a01.y); p.y = cvtpk(a23.x, a23.y);
      *reinterpret_cast<uint2*>(Ab + sc) = p;
    } else {
      const int cd0 = (ch - NCC)*32 + wv*4;   // 4 dense channels per thread
      uint2 u = *reinterpret_cast<const uint2*>(fin + (size_t)n_m*Cin + cd0);
      uint_t* up = (uint_t*)&u;
      #pragma unroll
      for (int q = 0; q < 2; ++q){
        uint_t w = up[q];
        uint_t lo = (w & 0x00008000u) ? 0u : (w & 0x0000FFFFu);
        uint_t hi = (w & 0x80000000u) ? 0u : (w & 0xFFFF0000u);
        up[q] = hi | lo;
      }
      *reinterpret_cast<uint2*>(Ab + sdn) = u;
    }
  };

  auto domfma = [&](short8 (&af)[MF], short8 (&bfr)[NF]){
    #pragma unroll
    for (int mi = 0; mi < MF; ++mi)
      #pragma unroll
      for (int ni = 0; ni < NF; ++ni)
        acc[mi][ni] = __builtin_amdgcn_mfma_f32_16x16x32_bf16(
            af[mi], bfr[ni], acc[mi][ni], 0, 0, 0);
  };

  __syncthreads();                       // halo(0) visible
  buildA(A_lds, 0);                      // super-chunk 0, both halves
  buildA(A_lds + 4096, 1);

  for (int scc = 0; scc < NSC; ++scc){
    const int Bofs = (scc & 1) << 13;    // buffer select (byte offset)
    char* Ab = A_lds + Bofs;
    __syncthreads();                     // A(scc) visible; prev readers done
    short8 bfr0[NF], bfr1[NF];
    loadB(bfr0, 2*scc);                  // issued early; consumed after shadow
    loadB(bfr1, 2*scc + 1);
    short8 af[MF];
    #pragma unroll
    for (int mi = 0; mi < MF; ++mi)
      af[mi] = *reinterpret_cast<const short8*>(Ab + aoff[mi]);
    const int nxtc = 2*(scc + 1);
    if ((nxtc < NCC) && ((nxtc & 15) == 0)){   // next phase's halo
      stage(nxtc >> 4);
      __syncthreads();                         // staged halo visible
    }
    if (scc + 1 < NSC){                  // build next super-chunk's A (shadow)
      char* An = A_lds + (Bofs ^ 8192);
      buildA(An, nxtc);
      buildA(An + 4096, nxtc + 1);
    }
    domfma(af, bfr0);                    // K-half 0
    #pragma unroll
    for (int mi = 0; mi < MF; ++mi)      // K-half 1 frags (buffer still valid)
      af[mi] = *reinterpret_cast<const short8*>(Ab + 4096 + aoff[mi]);
    domfma(af, bfr1);
  }

  // epilogue
  float bias[NF];
  #pragma unroll
  for (int ni = 0; ni < NF; ++ni){
    const int d = Nbase + ni*16 + lr;
    bias[ni] = cb[d] + db[d];
  }
  #pragma unroll
  for (int mi = 0; mi < MF; ++mi){
    #pragma unroll
    for (int r = 0; r < 4; ++r){
      const int row = mi*16 + lg*4 + r;
      const int n = ((i0 + (row >> 5)) << 8) + j0 + (row & 31);
      #pragma unroll
      for (int ni = 0; ni < NF; ++ni){
        const int d = Nbase + ni*16 + lr;
        float v = acc[mi][ni][r] + bias[ni];
        if (RESID) v += bf2f(fin[(size_t)n*Cin + d]);
        fout[(size_t)n*Cout + d] = f2bf(v);
      }
    }
  }
}

// ---------------- layer 4 (Cout=1): y[g][m] = relu(f3[m]) . Wy[g] ----------------
__global__ __launch_bounds__(256) void layer4a_kernel(
    const ushort_t* __restrict__ f3, const float* __restrict__ cw4,
    const float* __restrict__ dw4, float* __restrict__ y){
  __shared__ float Wy[17*256];
  __shared__ float red[4*1088];
  const int tid = threadIdx.x;
  for (int idx = tid; idx < 4096; idx += 256) Wy[idx] = cw4[idx];
  Wy[4096 + tid] = dw4[tid];
  __syncthreads();
  const int m = tid & 63, q = tid >> 6;
  const int n = blockIdx.x * 64 + m;
  const float4* Wy4 = reinterpret_cast<const float4*>(Wy);
  float acc[17];
  #pragma unroll
  for (int g = 0; g < 17; ++g) acc[g] = 0.0f;
  const uint4* frow = reinterpret_cast<const uint4*>(f3 + (size_t)n*256 + q*64);
  #pragma unroll
  for (int it = 0; it < 8; ++it){
    uint4 hv = frow[it];
    const uint_t* up = (const uint_t*)&hv;
    float f[8];
    #pragma unroll
    for (int w = 0; w < 4; ++w){
      uint_t u = up[w];
      f[2*w+0] = (u & 0x00008000u) ? 0.0f : __uint_as_float(u << 16);
      f[2*w+1] = (u & 0x80000000u) ? 0.0f : __uint_as_float(u & 0xFFFF0000u);
    }
    const int i4 = q*16 + it*2;
    #pragma unroll
    for (int g = 0; g < 17; ++g){
      float4 w0 = Wy4[g*64 + i4];
      float4 w1 = Wy4[g*64 + i4 + 1];
      acc[g] += w0.x*f[0] + w0.y*f[1] + w0.z*f[2] + w0.w*f[3]
              + w1.x*f[4] + w1.y*f[5] + w1.z*f[6] + w1.w*f[7];
    }
  }
  #pragma unroll
  for (int g = 0; g < 17; ++g) red[q*1088 + m*17 + g] = acc[g];
  __syncthreads();
  for (int idx = tid; idx < 1088; idx += 256){
    const int g = idx >> 6, mm = idx & 63;
    float s = red[0*1088 + mm*17 + g] + red[1*1088 + mm*17 + g]
            + red[2*1088 + mm*17 + g] + red[3*1088 + mm*17 + g];
    y[g*65536 + blockIdx.x*64 + mm] = s;
  }
}

__global__ __launch_bounds__(256) void layer4b_kernel(
    const float4* __restrict__ wgeo, const float* __restrict__ y,
    const float* __restrict__ cb4, const float* __restrict__ db4,
    float* __restrict__ out){
  const int n = blockIdx.x * 256 + threadIdx.x;
  const int i = n >> 8, j = n & 255;
  float acc = cb4[0] + db4[0] + y[16*65536 + n];
  #pragma unroll
  for (int k = 0; k < 9; ++k){
    const int di = k/3 - 1, dj = k - (k/3)*3 - 1;
    const int mi = min(max(i+di,0),255), mj = min(max(j+dj,0),255);
    const int m = (mi << 8) | mj;
    float4 geo = wgeo[n*9 + k];
    float wx[4], wy[4];
    #pragma unroll
    for (int a = 0; a < 4; ++a){
      wx[a] = fmaxf(1.0f - fabsf(geo.y - (float)a), 0.0f);
      wy[a] = fmaxf(1.0f - fabsf(geo.z - (float)a), 0.0f);
    }
    float s = 0.0f;
    #pragma unroll
    for (int ix = 0; ix < 4; ++ix){
      float sy = 0.0f;
      #pragma unroll
      for (int iy = 0; iy < 4; ++iy) sy += wy[iy] * y[(ix*4 + iy)*65536 + m];
      s += wx[ix] * sy;
    }
    acc += geo.x * s;
  }
  out[n] = tanhf(acc) * 0.8f + 1.0f;   // output f32
}

// ---------------- host launcher ----------------
extern "C" void kernel_launch(void* const* d_in, const int* in_sizes, int n_in,
                              void* d_out, int out_size, void* d_ws, size_t ws_size,
                              hipStream_t stream){
  const float* pos = (const float*)d_in[0];
  const float* vel = (const float*)d_in[1];
  const float* bng = (const float*)d_in[4];
  const float* bnb = (const float*)d_in[5];
  const bool dict = (in_sizes[8] == 96);
  const float *cwp[5], *cbp[5], *dwp[5], *dbp[5];
  for (int l = 0; l < 5; ++l){
    if (dict){
      cwp[l] = (const float*)d_in[6 + 4*l]; cbp[l] = (const float*)d_in[7 + 4*l];
      dwp[l] = (const float*)d_in[8 + 4*l]; dbp[l] = (const float*)d_in[9 + 4*l];
    } else {
      cwp[l] = (const float*)d_in[6 + 2*l];  cbp[l] = (const float*)d_in[7 + 2*l];
      dwp[l] = (const float*)d_in[16 + 2*l]; dbp[l] = (const float*)d_in[17 + 2*l];
    }
  }
  char* wsb = (char*)d_ws;
  float*    part  = (float*)   (wsb + 0);
  float*    stats = (float*)   (wsb + 4096);
  float4*   fin   = (float4*)  (wsb + 8192);
  float4*   wgeo  = (float4*)  (wsb + 1056768);
  ushort_t* Wt1   = (ushort_t*)(wsb + 10493952);
  ushort_t* Wt2   = (ushort_t*)(wsb + 10633216);
  ushort_t* Wt3   = (ushort_t*)(wsb + 10911744);
  ushort_t* f0    = (ushort_t*)(wsb + 12025856);
  ushort_t* f1    = (ushort_t*)(wsb + 20414464);
  ushort_t* f2    = (ushort_t*)(wsb + 28803072);
  ushort_t* f3    = (ushort_t*)(wsb + 45580288);
  float*    y     = (float*)   (wsb + 12025856);   // overlays f0 (dead by layer4)
  float*    outp  = (float*)d_out;

  hipLaunchKernelGGL(bn_partial, dim3(256), dim3(256), 0, stream, (const float2*)vel, part);
  hipLaunchKernelGGL(bn_final, dim3(1), dim3(256), 0, stream, part, bng, bnb, stats);
  hipLaunchKernelGGL(feats_kernel, dim3(256), dim3(256), 0, stream, (const float2*)vel, stats, fin);
  hipLaunchKernelGGL(geo_kernel, dim3(2304), dim3(256), 0, stream, (const float2*)pos, wgeo);
  hipLaunchKernelGGL((wprep<64,64>),   dim3(34),  dim3(256), 0, stream, cwp[1], dwp[1], Wt1);
  hipLaunchKernelGGL((wprep<64,128>),  dim3(68),  dim3(256), 0, stream, cwp[2], dwp[2], Wt2);
  hipLaunchKernelGGL((wprep<128,256>), dim3(272), dim3(256), 0, stream, cwp[3], dwp[3], Wt3);
  hipLaunchKernelGGL(layer0_kernel, dim3(2048), dim3(256), 0, stream,
                     fin, wgeo, cwp[0], cbp[0], dwp[0], dbp[0], f0);
  hipLaunchKernelGGL((conv_mfma<64,64,true>),   dim3(1024), dim3(256), 0, stream,
                     f0, wgeo, Wt1, cbp[1], dbp[1], f1);
  hipLaunchKernelGGL((conv_mfma<64,128,false>), dim3(1024), dim3(256), 0, stream,
                     f1, wgeo, Wt2, cbp[2], dbp[2], f2);
  hipLaunchKernelGGL((conv_mfma8<128,256,false>),dim3(1024), dim3(512), 0, stream,
                     f2, wgeo, Wt3, cbp[3], dbp[3], f3);
  hipLaunchKernelGGL(layer4a_kernel, dim3(1024), dim3(256), 0, stream, f3, cwp[4], dwp[4], y);
  hipLaunchKernelGGL(layer4b_kernel, dim3(256), dim3(256), 0, stream, wgeo, y, cbp[4], dbp[4], outp);
}

// Round 18
// 238.306 us; speedup vs baseline: 1.2295x; 1.2295x over previous
//
#include <hip/hip_runtime.h>
#include <hip/hip_bf16.h>
#include <cstdint>

// ParaNet_Point round-18: REVERT to r14 (best: 238.3us). r17's composed
// 8-wave+BK64 regressed (occupancy 22%, conv3 161us) - falsifier fired.
// Conv structure declared converged: r12/r14/r15/r16/r17 bracket conv3 at
// 106-162us; all occupancy/barrier/latency levers isolated and non-binding.
// This is the r14 source verbatim.

#define GRIDW 256
#define NPTS  65536
#define RADI  0.0125f
#define EPSF  1e-12f

typedef unsigned short ushort_t;
typedef unsigned int   uint_t;
typedef __attribute__((ext_vector_type(8))) short short8;   // 8 bf16 = 4 VGPR
typedef __attribute__((ext_vector_type(4))) float f32x4;
typedef __attribute__((ext_vector_type(2))) float f32x2;

template<int N> struct IC { static constexpr int v = N; };

__device__ __forceinline__ float bf2f(ushort_t h){
  union { uint_t u; float f; } c; c.u = ((uint_t)h) << 16; return c.f;
}
__device__ __forceinline__ ushort_t f2bf(float f){
  union { float f; uint_t u; } c; c.f = f;
  uint_t u = c.u;
  u += 0x7fffu + ((u >> 16) & 1u);   // round-to-nearest-even
  return (ushort_t)(u >> 16);
}
__device__ __forceinline__ uint_t cvtpk(float a, float b){   // {bf16(b)<<16 | bf16(a)}
  uint_t r; asm("v_cvt_pk_bf16_f32 %0, %1, %2" : "=v"(r) : "v"(a), "v"(b)); return r;
}
// dual-f32 fma, value-low broadcast: d{lo,hi} += t{lo,hi} * v.lo
__device__ __forceinline__ void pkfma_lo(f32x2& d, f32x2 t, f32x2 v){
  asm("v_pk_fma_f32 %0, %1, %2, %0 op_sel:[0,0,0] op_sel_hi:[1,0,1]"
      : "+v"(d) : "v"(t), "v"(v));
}
// dual-f32 fma, value-high broadcast: d{lo,hi} += t{lo,hi} * v.hi
__device__ __forceinline__ void pkfma_hi(f32x2& d, f32x2 t, f32x2 v){
  asm("v_pk_fma_f32 %0, %1, %2, %0 op_sel:[0,1,0] op_sel_hi:[1,1,1]"
      : "+v"(d) : "v"(t), "v"(v));
}
// swizzled byte offset into 64B-row LDS tile (row-dep XOR of 16B slot)
__device__ __forceinline__ int swz(int row, int byteoff){
  return row*64 + ((((byteoff >> 4) ^ ((row >> 1) & 3)) & 3) << 4) + (byteoff & 15);
}

// ---------------- BatchNorm statistics ----------------
__global__ __launch_bounds__(256) void bn_partial(const float2* __restrict__ vel,
                                                  float* __restrict__ part){
  __shared__ float s[256][4];
  const int t = threadIdx.x;
  const int id = blockIdx.x * 256 + t;
  float2 v = vel[id];
  s[t][0] = v.x; s[t][1] = v.y; s[t][2] = v.x * v.x; s[t][3] = v.y * v.y;
  __syncthreads();
  for (int off = 128; off > 0; off >>= 1){
    if (t < off){
      s[t][0] += s[t+off][0]; s[t][1] += s[t+off][1];
      s[t][2] += s[t+off][2]; s[t][3] += s[t+off][3];
    }
    __syncthreads();
  }
  if (t == 0){
    part[blockIdx.x*4+0] = s[0][0]; part[blockIdx.x*4+1] = s[0][1];
    part[blockIdx.x*4+2] = s[0][2]; part[blockIdx.x*4+3] = s[0][3];
  }
}

__global__ __launch_bounds__(256) void bn_final(const float* __restrict__ part,
                                                const float* __restrict__ gamma,
                                                const float* __restrict__ beta,
                                                float* __restrict__ stats){
  __shared__ float s[256][4];
  const int t = threadIdx.x;
  const float4 p = reinterpret_cast<const float4*>(part)[t];
  s[t][0] = p.x; s[t][1] = p.y; s[t][2] = p.z; s[t][3] = p.w;
  __syncthreads();
  for (int off = 128; off > 0; off >>= 1){
    if (t < off){
      s[t][0] += s[t+off][0]; s[t][1] += s[t+off][1];
      s[t][2] += s[t+off][2]; s[t][3] += s[t+off][3];
    }
    __syncthreads();
  }
  if (t == 0){
    const float invN = 1.0f / 65536.0f;
    float m0 = s[0][0]*invN, m1 = s[0][1]*invN;
    float var0 = s[0][2]*invN - m0*m0;
    float var1 = s[0][3]*invN - m1*m1;
    float A0 = gamma[0] * rsqrtf(var0 + 1e-5f);
    float A1 = gamma[1] * rsqrtf(var1 + 1e-5f);
    stats[0] = A0; stats[1] = beta[0] - A0*m0;
    stats[2] = A1; stats[3] = beta[1] - A1*m1;
    stats[4] = beta[2];   // z-col of vel3 is identically 0
  }
}

__global__ __launch_bounds__(256) void feats_kernel(const float2* __restrict__ vel,
                                                    const float* __restrict__ stats,
                                                    float4* __restrict__ fin){
  const int id = blockIdx.x * 256 + threadIdx.x;
  float2 v = vel[id];
  float A0 = stats[0], B0 = stats[1], A1 = stats[2], B1 = stats[3], C2 = stats[4];
  fin[id] = make_float4(A0*v.x + B0, A1*v.y + B1, C2, 0.0f);
}

// ---------------- filter geometry: (win, gx, gy) per (n,k) ----------------
__global__ __launch_bounds__(256) void geo_kernel(const float2* __restrict__ pos,
                                                  float4* __restrict__ wgeo){
  const int id = blockIdx.x * 256 + threadIdx.x;   // < N*9 exactly
  const int n = id / 9;
  const int k = id - n * 9;
  const int i = n >> 8, j = n & 255;
  const int di = k / 3 - 1, dj = k - (k/3)*3 - 1;
  const int ni = i + di, nj = j + dj;
  const bool valid = (ni >= 0) && (ni < GRIDW) && (nj >= 0) && (nj < GRIDW);
  const int mi = min(max(ni, 0), GRIDW-1), mj = min(max(nj, 0), GRIDW-1);
  const int m = (mi << 8) | mj;
  float2 pn = pos[n], pm = pos[m];
  float x = (pm.x - pn.x) * (1.0f / RADI);
  float y = (pm.y - pn.y) * (1.0f / RADI);
  float sq = x*x + y*y;                 // z == 0 throughout
  bool nz = sq > EPSF;
  float cx = nz ? x : 0.0f;
  float cy = nz ? y : 0.0f;
  float rr = cx*cx + cy*cy;
  float r = sqrtf(fmaxf(rr, EPSF));
  float acx = fabsf(cx), acy = fabsf(cy);
  bool condx = acx >= acy;
  float dx  = (acx > 1e-9f) ? cx : 1.0f;
  float dyv = (acy > 1e-9f) ? cy : 1.0f;
  const float fop = 1.27323954473516268615f;   // 4/pi
  float sx = (cx > 0.f) ? 1.f : ((cx < 0.f) ? -1.f : 0.f);
  float sy = (cy > 0.f) ? 1.f : ((cy < 0.f) ? -1.f : 0.f);
  float u, v;
  if (condx){ u = sx * r;                    v = sx * r * fop * atanf(cy/dx); }
  else      { u = sy * r * fop * atanf(cx/dyv); v = sy * r; }
  if (rr <= EPSF){ u = 0.0f; v = 0.0f; }
  float gx = fminf(fmaxf((u + 1.0f) * 1.5f, 0.0f), 3.0f);
  float gy = fminf(fmaxf((v + 1.0f) * 1.5f, 0.0f), 3.0f);
  float pw = 1.0f - fminf(fmaxf(sq, 0.0f), 1.0f);
  float win = pw * pw * pw;
  win = (sq <= 1.0f && valid) ? win : 0.0f;
  wgeo[id] = make_float4(win, gx, gy, 0.0f);
}

// -- W pre-pack into MFMA B-fragment order --------------------------------
// Wfrag[((ch*G + grp)*64 + l)*8 + e] = bf16(W[kk = ch*32 + (l>>4)*8 + e]
//                                          [d  = grp*16 + (l&15)])
template<int Cin, int Cout>
__global__ __launch_bounds__(256) void wprep(const float* __restrict__ cw,
                                             const float* __restrict__ dw,
                                             ushort_t* __restrict__ Wf){
  constexpr int G = Cout/16;
  const int id = blockIdx.x*256 + threadIdx.x;     // grid sized exactly
  const int ch = id / (G*64);
  const int r  = id - ch*G*64;
  const int grp = r >> 6, l = r & 63;
  const int d  = grp*16 + (l & 15);
  const int kb = ch*32 + (l >> 4)*8;
  ushort_t o[8];
  #pragma unroll
  for (int e = 0; e < 8; ++e){
    const int kk = kb + e;
    float v;
    if (kk < 16*Cin){ int c = kk >> 4, g = kk & 15; v = cw[(size_t)(g*Cin + c)*Cout + d]; }
    else v = dw[(size_t)(kk - 16*Cin)*Cout + d];
    o[e] = f2bf(v);
  }
  *reinterpret_cast<uint4*>(Wf + (size_t)id*8) = *reinterpret_cast<uint4*>(o);
}

// ---------------- layer 0: Cin=3 direct (VALU, small) ----------------
__global__ __launch_bounds__(256) void layer0_kernel(
    const float4* __restrict__ fin, const float4* __restrict__ wgeo,
    const float* __restrict__ cw, const float* __restrict__ cb,
    const float* __restrict__ dw, const float* __restrict__ db,
    ushort_t* __restrict__ f0){
  __shared__ float Wc[48*32];
  __shared__ float Wd[96];
  __shared__ float Bs[64];
  const int tid = threadIdx.x;
  for (int idx = tid; idx < 1536; idx += 256) Wc[idx] = cw[idx];
  if (tid < 96) Wd[tid] = dw[tid];
  if (tid < 32){ Bs[tid] = cb[tid]; Bs[32+tid] = db[tid]; }
  __syncthreads();
  const int p = tid >> 3, q = tid & 7;
  const int n = blockIdx.x * 32 + p;
  const int i = n >> 8, j = n & 255;
  float A[48];
  #pragma unroll
  for (int a = 0; a < 48; ++a) A[a] = 0.0f;
  const float4 fc = fin[n];
  #pragma unroll
  for (int k = 0; k < 9; ++k){
    const int di = k/3 - 1, dj = k - (k/3)*3 - 1;
    const int mi = min(max(i+di,0),255), mj = min(max(j+dj,0),255);
    const int m = (mi << 8) | mj;
    float4 geo = wgeo[n*9 + k];
    float4 fm = fin[m];
    float wx[4], wy[4];
    #pragma unroll
    for (int a = 0; a < 4; ++a){
      wx[a] = fmaxf(1.0f - fabsf(geo.y - (float)a), 0.0f);
      wy[a] = fmaxf(1.0f - fabsf(geo.z - (float)a), 0.0f);
    }
    #pragma unroll
    for (int ix = 0; ix < 4; ++ix)
      #pragma unroll
      for (int iy = 0; iy < 4; ++iy){
        float w = geo.x * wx[ix] * wy[iy];
        int g = ix*4 + iy;
        A[g*3+0] += w * fm.x; A[g*3+1] += w * fm.y; A[g*3+2] += w * fm.z;
      }
  }
  if (q < 4){
    #pragma unroll
    for (int jj = 0; jj < 8; ++jj){
      int d = q*8 + jj;
      float acc = Bs[d];
      #pragma unroll
      for (int a = 0; a < 48; ++a) acc += A[a] * Wc[a*32 + d];
      f0[n*64 + d] = f2bf(acc);
    }
  } else {
    #pragma unroll
    for (int jj = 0; jj < 8; ++jj){
      int d2 = (q-4)*8 + jj;
      float acc = Bs[32+d2] + fc.x*Wd[0*32+d2] + fc.y*Wd[1*32+d2] + fc.z*Wd[2*32+d2];
      f0[n*64 + 32 + d2] = f2bf(acc);
    }
  }
}

// ---- MFMA conv+dense layers: A in LDS (dbuf), W global->VGPR fragments ----
// bfrA/bfrB register double-buffer: chunk ch's body prefetches ch+1's B-frags.
template<int Cin, int Cout, bool RESID>
__global__ __launch_bounds__(256) void conv_mfma(
    const ushort_t* __restrict__ fin, const float4* __restrict__ wgeo,
    const ushort_t* __restrict__ Wf,
    const float* __restrict__ cb, const float* __restrict__ db,
    ushort_t* __restrict__ fout){
  constexpr int K   = 17*Cin;
  constexpr int NCC = Cin/2;            // conv chunks
  constexpr int NCH = K/32;             // total chunks (even)
  constexpr int HSTR = 137;             // halo row stride in f32x2 units
  constexpr int G   = Cout/16;          // 16-col groups per chunk
  constexpr int MF  = 4;                // every wave covers all 64 rows
  constexpr int NF  = Cout/64;          // col groups per wave

  __shared__ f32x2 halo64[16*HSTR];                   // 17536 B, relu'd pairs
  __shared__ __align__(16) ushort_t A_lds[2][64*32];  // 2 x 4 KB, swizzled

  const int tid = threadIdx.x;
  const int i0 = (blockIdx.x >> 3) * 2;
  const int j0 = (blockIdx.x & 7) * 32;

  auto stage = [&](int ph){
    for (int idx = tid; idx < 544; idx += 256){
      const int loc = idx >> 2, c8l = idx & 3;
      const int r = loc / 34, col = loc - r*34;
      const int gi = min(max(i0 - 1 + r, 0), 255);
      const int gj = min(max(j0 - 1 + col, 0), 255);
      const int mm = (gi << 8) | gj;
      uint4 v = *reinterpret_cast<const uint4*>(fin + (size_t)mm*Cin + ph*32 + c8l*8);
      const uint_t* vp = (const uint_t*)&v;
      #pragma unroll
      for (int q = 0; q < 4; ++q){
        uint_t u = vp[q];
        f32x2 f;
        f.x = fmaxf(__uint_as_float(u << 16), 0.0f);
        f.y = fmaxf(__uint_as_float(u & 0xFFFF0000u), 0.0f);
        halo64[(c8l*4 + q)*HSTR + loc] = f;
      }
    }
  };

  const int m  = tid & 63;              // local point == lane
  const int gq = tid >> 6;              // g-quarter AND wave id
  const int g0 = gq * 4;
  const int n_m = ((i0 + (m >> 5)) << 8) + j0 + (m & 31);
  const int lane = m;
  const int lr = lane & 15, lg = lane >> 4;
  const int ctr = (1 + (m >> 5))*34 + 1 + (m & 31);

  stage(0);
  // taps as f32x2 pairs {g0,g1},{g2,g3} per k (pk_fma operands, no copies)
  f32x2 tap2[9][2];
  #pragma unroll
  for (int k = 0; k < 9; ++k){
    float4 geo = wgeo[(size_t)n_m*9 + k];
    float wxg = fmaxf(1.0f - fabsf(geo.y - (float)gq), 0.0f);
    float s = geo.x * wxg;
    tap2[k][0].x = s * fmaxf(1.0f - fabsf(geo.z - 0.0f), 0.0f);
    tap2[k][0].y = s * fmaxf(1.0f - fabsf(geo.z - 1.0f), 0.0f);
    tap2[k][1].x = s * fmaxf(1.0f - fabsf(geo.z - 2.0f), 0.0f);
    tap2[k][1].y = s * fmaxf(1.0f - fabsf(geo.z - 3.0f), 0.0f);
  }

  const int Nbase = gq * (NF*16);       // wave's unique column block

  int aoff[MF];
  #pragma unroll
  for (int mi = 0; mi < MF; ++mi) aoff[mi] = swz(mi*16 + lr, lg*16);
  const int s0 = swz(m, 2*g0);
  const int s1 = swz(m, 32 + 2*g0);
  const int sd = swz(m, gq*16);

  // wave's W-fragment base: (chunk 0, grp = gq*NF + ni), lane slot
  const ushort_t* wp = Wf + (size_t)(gq*NF)*512 + lane*8;

  f32x4 acc[MF][NF];
  #pragma unroll
  for (int a = 0; a < MF; ++a)
    #pragma unroll
    for (int b = 0; b < NF; ++b) acc[a][b] = (f32x4){0.f,0.f,0.f,0.f};

  short8 bfrA[NF], bfrB[NF];
  auto loadB = [&](short8 (&dst)[NF], int ch){
    const ushort_t* wpc = wp + (size_t)ch * (G*512);
    #pragma unroll
    for (int ni = 0; ni < NF; ++ni)
      dst[ni] = *reinterpret_cast<const short8*>(wpc + ni*512);
  };

  auto buildA = [&](auto BC, int ch){
    constexpr int B = decltype(BC)::v;
    char* Ab = (char*)A_lds[B];
    if (ch < NCC){
      const f32x2* hb = &halo64[(ch & 15)*HSTR + ctr - 35];
      f32x2 a01 = {0.f,0.f}, a23 = {0.f,0.f};   // lo channel, g{0,1},{2,3}
      f32x2 b01 = {0.f,0.f}, b23 = {0.f,0.f};   // hi channel
      #pragma unroll
      for (int kr = 0; kr < 3; ++kr)
        #pragma unroll
        for (int kc = 0; kc < 3; ++kc){
          const f32x2 val = hb[kr*34 + kc];
          const int k = kr*3 + kc;
          pkfma_lo(a01, tap2[k][0], val);
          pkfma_lo(a23, tap2[k][1], val);
          pkfma_hi(b01, tap2[k][0], val);
          pkfma_hi(b23, tap2[k][1], val);
        }
      uint2 plo, phi;
      plo.x = cvtpk(a01.x, a01.y); plo.y = cvtpk(a23.x, a23.y);
      phi.x = cvtpk(b01.x, b01.y); phi.y = cvtpk(b23.x, b23.y);
      *reinterpret_cast<uint2*>(Ab + s0) = plo;
      *reinterpret_cast<uint2*>(Ab + s1) = phi;
    } else {
      const int cd0 = (ch - NCC)*32 + gq*8;   // 8 dense channels per thread
      uint4 u = *reinterpret_cast<const uint4*>(fin + (size_t)n_m*Cin + cd0);
      uint_t* up = (uint_t*)&u;
      #pragma unroll
      for (int q = 0; q < 4; ++q){
        uint_t w = up[q];
        uint_t lo = (w & 0x00008000u) ? 0u : (w & 0x0000FFFFu);
        uint_t hi = (w & 0x80000000u) ? 0u : (w & 0xFFFF0000u);
        up[q] = hi | lo;
      }
      *reinterpret_cast<uint4*>(Ab + sd) = u;
    }
  };

  auto domfma = [&](short8 (&af)[MF], short8 (&bfr)[NF]){
    #pragma unroll
    for (int mi = 0; mi < MF; ++mi)
      #pragma unroll
      for (int ni = 0; ni < NF; ++ni)
        acc[mi][ni] = __builtin_amdgcn_mfma_f32_16x16x32_bf16(
            af[mi], bfr[ni], acc[mi][ni], 0, 0, 0);
  };

  auto body = [&](auto BC, int ch, bool prep){
    constexpr int B = decltype(BC)::v;
    __syncthreads();                     // A(ch) visible; prev readers done
    if (prep){                           // prefetch NEXT chunk's B-fragments
      if constexpr (B == 0) loadB(bfrB, ch + 1);
      else                  loadB(bfrA, ch + 1);
    }
    short8 af[MF];
    const char* Ab = (const char*)A_lds[B];
    #pragma unroll
    for (int mi = 0; mi < MF; ++mi)
      af[mi] = *reinterpret_cast<const short8*>(Ab + aoff[mi]);
    if (prep) buildA(IC<B^1>{}, ch + 1);   // VALU fills the load shadow
    if constexpr (B == 0) domfma(af, bfrA);
    else                  domfma(af, bfrB);
  };

  __syncthreads();                       // halo(0) visible
  loadB(bfrA, 0);
  buildA(IC<0>{}, 0);

  for (int ch2 = 0; ch2 < NCH; ch2 += 2){
    body(IC<0>{}, ch2, true);            // uses bfrA, prefetches bfrB(ch2+1)
    const int nxt = ch2 + 2;
    if ((nxt < NCC) && ((nxt & 15) == 0)){ __syncthreads(); stage(nxt >> 4); }
    body(IC<1>{}, ch2 + 1, nxt < NCH);   // uses bfrB, prefetches bfrA(ch2+2)
  }

  // epilogue: + biases (+ residual), store bf16
  float bias[NF];
  #pragma unroll
  for (int ni = 0; ni < NF; ++ni){
    const int d = Nbase + ni*16 + lr;
    bias[ni] = cb[d] + db[d];
  }
  #pragma unroll
  for (int mi = 0; mi < MF; ++mi){
    #pragma unroll
    for (int r = 0; r < 4; ++r){
      const int row = mi*16 + lg*4 + r;
      const int n = ((i0 + (row >> 5)) << 8) + j0 + (row & 31);
      #pragma unroll
      for (int ni = 0; ni < NF; ++ni){
        const int d = Nbase + ni*16 + lr;
        float v = acc[mi][ni][r] + bias[ni];
        if (RESID) v += bf2f(fin[(size_t)n*Cin + d]);
        fout[(size_t)n*Cout + d] = f2bf(v);
      }
    }
  }
}

// ---------------- layer 4 (Cout=1): y[g][m] = relu(f3[m]) . Wy[g] ----------------
__global__ __launch_bounds__(256) void layer4a_kernel(
    const ushort_t* __restrict__ f3, const float* __restrict__ cw4,
    const float* __restrict__ dw4, float* __restrict__ y){
  __shared__ float Wy[17*256];
  __shared__ float red[4*1088];
  const int tid = threadIdx.x;
  for (int idx = tid; idx < 4096; idx += 256) Wy[idx] = cw4[idx];
  Wy[4096 + tid] = dw4[tid];
  __syncthreads();
  const int m = tid & 63, q = tid >> 6;
  const int n = blockIdx.x * 64 + m;
  const float4* Wy4 = reinterpret_cast<const float4*>(Wy);
  float acc[17];
  #pragma unroll
  for (int g = 0; g < 17; ++g) acc[g] = 0.0f;
  const uint4* frow = reinterpret_cast<const uint4*>(f3 + (size_t)n*256 + q*64);
  #pragma unroll
  for (int it = 0; it < 8; ++it){
    uint4 hv = frow[it];
    const uint_t* up = (const uint_t*)&hv;
    float f[8];
    #pragma unroll
    for (int w = 0; w < 4; ++w){
      uint_t u = up[w];
      f[2*w+0] = (u & 0x00008000u) ? 0.0f : __uint_as_float(u << 16);
      f[2*w+1] = (u & 0x80000000u) ? 0.0f : __uint_as_float(u & 0xFFFF0000u);
    }
    const int i4 = q*16 + it*2;
    #pragma unroll
    for (int g = 0; g < 17; ++g){
      float4 w0 = Wy4[g*64 + i4];
      float4 w1 = Wy4[g*64 + i4 + 1];
      acc[g] += w0.x*f[0] + w0.y*f[1] + w0.z*f[2] + w0.w*f[3]
              + w1.x*f[4] + w1.y*f[5] + w1.z*f[6] + w1.w*f[7];
    }
  }
  #pragma unroll
  for (int g = 0; g < 17; ++g) red[q*1088 + m*17 + g] = acc[g];
  __syncthreads();
  for (int idx = tid; idx < 1088; idx += 256){
    const int g = idx >> 6, mm = idx & 63;
    float s = red[0*1088 + mm*17 + g] + red[1*1088 + mm*17 + g]
            + red[2*1088 + mm*17 + g] + red[3*1088 + mm*17 + g];
    y[g*65536 + blockIdx.x*64 + mm] = s;
  }
}

__global__ __launch_bounds__(256) void layer4b_kernel(
    const float4* __restrict__ wgeo, const float* __restrict__ y,
    const float* __restrict__ cb4, const float* __restrict__ db4,
    float* __restrict__ out){
  const int n = blockIdx.x * 256 + threadIdx.x;
  const int i = n >> 8, j = n & 255;
  float acc = cb4[0] + db4[0] + y[16*65536 + n];
  #pragma unroll
  for (int k = 0; k < 9; ++k){
    const int di = k/3 - 1, dj = k - (k/3)*3 - 1;
    const int mi = min(max(i+di,0),255), mj = min(max(j+dj,0),255);
    const int m = (mi << 8) | mj;
    float4 geo = wgeo[n*9 + k];
    float wx[4], wy[4];
    #pragma unroll
    for (int a = 0; a < 4; ++a){
      wx[a] = fmaxf(1.0f - fabsf(geo.y - (float)a), 0.0f);
      wy[a] = fmaxf(1.0f - fabsf(geo.z - (float)a), 0.0f);
    }
    float s = 0.0f;
    #pragma unroll
    for (int ix = 0; ix < 4; ++ix){
      float sy = 0.0f;
      #pragma unroll
      for (int iy = 0; iy < 4; ++iy) sy += wy[iy] * y[(ix*4 + iy)*65536 + m];
      s += wx[ix] * sy;
    }
    acc += geo.x * s;
  }
  out[n] = tanhf(acc) * 0.8f + 1.0f;   // output f32
}

// ---------------- host launcher ----------------
extern "C" void kernel_launch(void* const* d_in, const int* in_sizes, int n_in,
                              void* d_out, int out_size, void* d_ws, size_t ws_size,
                              hipStream_t stream){
  const float* pos = (const float*)d_in[0];
  const float* vel = (const float*)d_in[1];
  const float* bng = (const float*)d_in[4];
  const float* bnb = (const float*)d_in[5];
  const bool dict = (in_sizes[8] == 96);
  const float *cwp[5], *cbp[5], *dwp[5], *dbp[5];
  for (int l = 0; l < 5; ++l){
    if (dict){
      cwp[l] = (const float*)d_in[6 + 4*l]; cbp[l] = (const float*)d_in[7 + 4*l];
      dwp[l] = (const float*)d_in[8 + 4*l]; dbp[l] = (const float*)d_in[9 + 4*l];
    } else {
      cwp[l] = (const float*)d_in[6 + 2*l];  cbp[l] = (const float*)d_in[7 + 2*l];
      dwp[l] = (const float*)d_in[16 + 2*l]; dbp[l] = (const float*)d_in[17 + 2*l];
    }
  }
  char* wsb = (char*)d_ws;
  float*    part  = (float*)   (wsb + 0);
  float*    stats = (float*)   (wsb + 4096);
  float4*   fin   = (float4*)  (wsb + 8192);
  float4*   wgeo  = (float4*)  (wsb + 1056768);
  ushort_t* Wt1   = (ushort_t*)(wsb + 10493952);
  ushort_t* Wt2   = (ushort_t*)(wsb + 10633216);
  ushort_t* Wt3   = (ushort_t*)(wsb + 10911744);
  ushort_t* f0    = (ushort_t*)(wsb + 12025856);
  ushort_t* f1    = (ushort_t*)(wsb + 20414464);
  ushort_t* f2    = (ushort_t*)(wsb + 28803072);
  ushort_t* f3    = (ushort_t*)(wsb + 45580288);
  float*    y     = (float*)   (wsb + 12025856);   // overlays f0 (dead by layer4)
  float*    outp  = (float*)d_out;

  hipLaunchKernelGGL(bn_partial, dim3(256), dim3(256), 0, stream, (const float2*)vel, part);
  hipLaunchKernelGGL(bn_final, dim3(1), dim3(256), 0, stream, part, bng, bnb, stats);
  hipLaunchKernelGGL(feats_kernel, dim3(256), dim3(256), 0, stream, (const float2*)vel, stats, fin);
  hipLaunchKernelGGL(geo_kernel, dim3(2304), dim3(256), 0, stream, (const float2*)pos, wgeo);
  hipLaunchKernelGGL((wprep<64,64>),   dim3(34),  dim3(256), 0, stream, cwp[1], dwp[1], Wt1);
  hipLaunchKernelGGL((wprep<64,128>),  dim3(68),  dim3(256), 0, stream, cwp[2], dwp[2], Wt2);
  hipLaunchKernelGGL((wprep<128,256>), dim3(272), dim3(256), 0, stream, cwp[3], dwp[3], Wt3);
  hipLaunchKernelGGL(layer0_kernel, dim3(2048), dim3(256), 0, stream,
                     fin, wgeo, cwp[0], cbp[0], dwp[0], dbp[0], f0);
  hipLaunchKernelGGL((conv_mfma<64,64,true>),   dim3(1024), dim3(256), 0, stream,
                     f0, wgeo, Wt1, cbp[1], dbp[1], f1);
  hipLaunchKernelGGL((conv_mfma<64,128,false>), dim3(1024), dim3(256), 0, stream,
                     f1, wgeo, Wt2, cbp[2], dbp[2], f2);
  hipLaunchKernelGGL((conv_mfma<128,256,false>),dim3(1024), dim3(256), 0, stream,
                     f2, wgeo, Wt3, cbp[3], dbp[3], f3);
  hipLaunchKernelGGL(layer4a_kernel, dim3(1024), dim3(256), 0, stream, f3, cwp[4], dwp[4], y);
  hipLaunchKernelGGL(layer4b_kernel, dim3(256), dim3(256), 0, stream, wgeo, y, cbp[4], dbp[4], outp);
}